// Round 1
// baseline (203.262 us; speedup 1.0000x reference)
//
#include <hip/hip_runtime.h>
#include <hip/hip_bf16.h>

// MetaConv2d fused hypernetwork + dynamic conv, bf16 MFMA.
// out[bn,t,o] = sum_{c,k} x[bn,t+k,c] * w[bn,o,c,k] + bias[bn,o]
//   w[bn,p]   = meta[bn,:]·w_lin_w[p,:] + w_lin_b[p],  p = o*192 + c*3 + k
//   bias[bn,o]= meta[bn,:]·b_lin_w[o,:] + b_lin_b[o]
//
// Block = 16 nodes (bn), 512 threads (8 waves), grid 512.
// 8 phases = 4 c-chunks (16 cin) x 2 o-halves (32 cout):
//   hyper: MFMA 16x16x32 (M=w_lin rows, N=16 nodes, K=32 meta) -> LDS w-chunk (bf16)
//   conv : MFMA 16x16x32 (M=t, N=o, K=j) consuming LDS w-chunk, x direct from global
// Contraction index j = k*16 + cc (cc = c within chunk); per c-chunk K=48 is done as
// one full K=32 step + one K=32 step with upper half zeroed (A=0 vs zero-padded LDS).

#define BN_TOT   8192
#define S_LEN    64
#define C_IN     64
#define C_OUT    64
#define M_DIM    32
#define S_OUT    62

#define NT       16          // nodes per block
#define NTHREADS 512
#define OH       32          // couts per phase
#define JC       56          // j-stride per cout in LDS (48 real + 8 zeros)
#define NODE_STR 1800        // shorts per node (32*56 + 8 pad; 3600B, 16B-aligned)
#define WSH_N    (NT * NODE_STR)   // 28800 shorts = 57.6 KB

typedef __attribute__((ext_vector_type(8))) short bf16x8;
typedef __attribute__((ext_vector_type(4))) float f32x4;

static __device__ __forceinline__ short f2bf(float f) {
    union { float f; unsigned u; } v; v.f = f;
    return (short)((v.u + 0x7FFFu + ((v.u >> 16) & 1u)) >> 16);
}

extern "C" __global__ void __launch_bounds__(NTHREADS, 2)
metaconv_fused(const float* __restrict__ meta,   // [8192][32]
               const float* __restrict__ x,      // [8192][64][64]
               const float* __restrict__ wlw,    // [12288][32]
               const float* __restrict__ wlb,    // [12288]
               const float* __restrict__ blw,    // [64][32]
               const float* __restrict__ blb,    // [64]
               float* __restrict__ out)          // [8192][62][64]
{
    __shared__ short wsh[WSH_N];
    __shared__ float bias_s[NT][C_OUT];

    const int tid  = threadIdx.x;
    const int wave = tid >> 6;
    const int lane = tid & 63;
    const int l16  = lane & 15;
    const int g    = lane >> 4;
    const int bn0  = blockIdx.x * NT;

    // zero LDS once: provides the zero pad at j 48..55 read by the 2nd K-step
    for (int i = tid; i < WSH_N; i += NTHREADS) wsh[i] = 0;

    // per-block bias table: bias[node][o] = meta·b_lin_w[o] + b_lin_b[o]
    for (int idx = tid; idx < NT * C_OUT; idx += NTHREADS) {
        const int node = idx >> 6;
        const int o    = idx & 63;
        const float* mrow = meta + (size_t)(bn0 + node) * M_DIM;
        const float* brow = blw + o * M_DIM;
        float s = blb[o];
        #pragma unroll
        for (int m = 0; m < M_DIM; ++m) s += mrow[m] * brow[m];
        bias_s[node][o] = s;
    }

    // meta B-fragment (N=16 nodes, K=32): same for every hyper MFMA; keep in regs
    bf16x8 metaF;
    {
        const float* mp = meta + (size_t)(bn0 + l16) * M_DIM + g * 8;
        const float4 m0 = *(const float4*)(mp);
        const float4 m1 = *(const float4*)(mp + 4);
        metaF[0]=f2bf(m0.x); metaF[1]=f2bf(m0.y); metaF[2]=f2bf(m0.z); metaF[3]=f2bf(m0.w);
        metaF[4]=f2bf(m1.x); metaF[5]=f2bf(m1.y); metaF[6]=f2bf(m1.z); metaF[7]=f2bf(m1.w);
    }

    // persistent conv accumulators: 2 nodes x 4 t-tiles x 4 o-tiles (all compile-time idx)
    const f32x4 ZV = {0.f, 0.f, 0.f, 0.f};
    f32x4 acc[2][4][4];
    #pragma unroll
    for (int a = 0; a < 2; ++a)
        #pragma unroll
        for (int t = 0; t < 4; ++t)
            #pragma unroll
            for (int o = 0; o < 4; ++o) acc[a][t][o] = ZV;

    __syncthreads();

    #pragma unroll 1
    for (int cchunk = 0; cchunk < 4; ++cchunk) {
        const int c0 = cchunk * 16;
        #pragma unroll
        for (int ohalf = 0; ohalf < 2; ++ohalf) {
            const int obase = ohalf * OH;

            // ---------------- hypernetwork phase ----------------
            // 96 row-tiles = (o_local 0..31) x (k 0..2); 12 per wave.
            // Tile rows = cc 0..15 (c = c0+cc), fixed (o,k). D: col=node, row=cc.
            #pragma unroll 1
            for (int i = 0; i < 12; ++i) {
                const int tileid = wave * 12 + i;
                const int o_l = tileid / 3;
                const int k   = tileid - o_l * 3;
                const int orow = obase + o_l;
                const int p = orow * 192 + (c0 + l16) * 3 + k;   // w_lin row for A-row cc=l16
                const float* wp = wlw + (size_t)p * M_DIM + g * 8;
                const float4 w0 = *(const float4*)(wp);
                const float4 w1 = *(const float4*)(wp + 4);
                bf16x8 aF;
                aF[0]=f2bf(w0.x); aF[1]=f2bf(w0.y); aF[2]=f2bf(w0.z); aF[3]=f2bf(w0.w);
                aF[4]=f2bf(w1.x); aF[5]=f2bf(w1.y); aF[6]=f2bf(w1.z); aF[7]=f2bf(w1.w);
                f32x4 d = __builtin_amdgcn_mfma_f32_16x16x32_bf16(aF, metaF, ZV, 0, 0, 0);
                // lane holds rows cc = g*4+r for node = l16; add w_lin_b, store bf16
                const int ccb = g * 4;
                const int pb  = orow * 192 + k;
                const short r0 = f2bf(d[0] + wlb[pb + (c0 + ccb + 0) * 3]);
                const short r1 = f2bf(d[1] + wlb[pb + (c0 + ccb + 1) * 3]);
                const short r2 = f2bf(d[2] + wlb[pb + (c0 + ccb + 2) * 3]);
                const short r3 = f2bf(d[3] + wlb[pb + (c0 + ccb + 3) * 3]);
                const int off = l16 * NODE_STR + o_l * JC + k * 16 + ccb;
                *reinterpret_cast<short4*>(&wsh[off]) = make_short4(r0, r1, r2, r3);
            }
            __syncthreads();

            // ---------------- conv phase ----------------
            #pragma unroll
            for (int nn = 0; nn < 2; ++nn) {
                const int node = wave * 2 + nn;
                const float* xb = x + (size_t)(bn0 + node) * (S_LEN * C_IN);
                const short* wnode = &wsh[node * NODE_STR];
                #pragma unroll
                for (int tt = 0; tt < 4; ++tt) {
                    const int t0 = tt * 16;
                    // A0: kk=g*8+e -> j=kk: k=g>>1, c=c0+(g&1)*8+e  (row t=t0+l16)
                    int row0 = t0 + l16 + (g >> 1);
                    row0 = row0 < 63 ? row0 : 63;               // t>=62 rows are discarded
                    const float* xp = xb + row0 * C_IN + c0 + (g & 1) * 8;
                    const float4 a0 = *(const float4*)(xp);
                    const float4 a1 = *(const float4*)(xp + 4);
                    bf16x8 A0;
                    A0[0]=f2bf(a0.x); A0[1]=f2bf(a0.y); A0[2]=f2bf(a0.z); A0[3]=f2bf(a0.w);
                    A0[4]=f2bf(a1.x); A0[5]=f2bf(a1.y); A0[6]=f2bf(a1.z); A0[7]=f2bf(a1.w);
                    // A1: kk<16 -> j=32+kk: k=2, c=c0+kk; kk>=16 must be 0 (zero pad in LDS side too)
                    bf16x8 A1;
                    if (g < 2) {
                        int row1 = t0 + l16 + 2;
                        row1 = row1 < 63 ? row1 : 63;
                        const float* xq = xb + row1 * C_IN + c0 + g * 8;
                        const float4 b0 = *(const float4*)(xq);
                        const float4 b1 = *(const float4*)(xq + 4);
                        A1[0]=f2bf(b0.x); A1[1]=f2bf(b0.y); A1[2]=f2bf(b0.z); A1[3]=f2bf(b0.w);
                        A1[4]=f2bf(b1.x); A1[5]=f2bf(b1.y); A1[6]=f2bf(b1.z); A1[7]=f2bf(b1.w);
                    } else {
                        A1[0]=0; A1[1]=0; A1[2]=0; A1[3]=0;
                        A1[4]=0; A1[5]=0; A1[6]=0; A1[7]=0;
                    }
                    #pragma unroll
                    for (int ol = 0; ol < 2; ++ol) {
                        const short* wrow = wnode + (ol * 16 + l16) * JC;
                        const bf16x8 B0 = *reinterpret_cast<const bf16x8*>(&wrow[g * 8]);
                        const bf16x8 B1 = *reinterpret_cast<const bf16x8*>(&wrow[32 + g * 8]);
                        acc[nn][tt][ohalf * 2 + ol] =
                            __builtin_amdgcn_mfma_f32_16x16x32_bf16(A0, B0, acc[nn][tt][ohalf * 2 + ol], 0, 0, 0);
                        acc[nn][tt][ohalf * 2 + ol] =
                            __builtin_amdgcn_mfma_f32_16x16x32_bf16(A1, B1, acc[nn][tt][ohalf * 2 + ol], 0, 0, 0);
                    }
                }
            }
            __syncthreads();
        }
    }

    // ---------------- epilogue: add bias, store f32 ----------------
    #pragma unroll
    for (int nn = 0; nn < 2; ++nn) {
        const int node = wave * 2 + nn;
        float* ob = out + (size_t)(bn0 + node) * (S_OUT * C_OUT);
        #pragma unroll
        for (int tt = 0; tt < 4; ++tt) {
            #pragma unroll
            for (int ot = 0; ot < 4; ++ot) {
                const int o = ot * 16 + l16;
                const float bv = bias_s[node][o];
                #pragma unroll
                for (int r = 0; r < 4; ++r) {
                    const int t = tt * 16 + g * 4 + r;   // D: row = g*4+r, col = l16
                    if (t < S_OUT) ob[t * C_OUT + o] = acc[nn][tt][ot][r] + bv;
                }
            }
        }
    }
}

extern "C" void kernel_launch(void* const* d_in, const int* in_sizes, int n_in,
                              void* d_out, int out_size, void* d_ws, size_t ws_size,
                              hipStream_t stream) {
    const float* meta = (const float*)d_in[0];
    const float* x    = (const float*)d_in[1];
    const float* wlw  = (const float*)d_in[2];
    const float* wlb  = (const float*)d_in[3];
    const float* blw  = (const float*)d_in[4];
    const float* blb  = (const float*)d_in[5];
    float* out = (float*)d_out;
    (void)in_sizes; (void)n_in; (void)out_size; (void)d_ws; (void)ws_size;

    metaconv_fused<<<dim3(BN_TOT / NT), dim3(NTHREADS), 0, stream>>>(
        meta, x, wlw, wlb, blw, blb, out);
}